// Round 6
// baseline (219.165 us; speedup 1.0000x reference)
//
#include <hip/hip_runtime.h>
#include <stdint.h>

#define B_ 4
#define L_ 4096
#define D_ 1024
#define C_ 2048
#define M_ (B_ * L_)  // 16384
#define LCH 16        // conv l-chunk per block

typedef __attribute__((ext_vector_type(8))) short s16x8;
typedef __attribute__((ext_vector_type(4))) float fx4;
typedef unsigned short bfu;  // bf16 bits

__device__ __forceinline__ float bits2f(short s) {
  return __uint_as_float(((uint32_t)(unsigned short)s) << 16);
}
__device__ __forceinline__ bfu f2bf(float f) {
  uint32_t u = __float_as_uint(f);
  uint32_t r = (u + 0x7FFFu + ((u >> 16) & 1u)) >> 16;  // RNE
  return (bfu)r;
}

__device__ __forceinline__ void gload_lds16(const void* g, void* l) {
  __builtin_amdgcn_global_load_lds(
      (const __attribute__((address_space(1))) void*)g,
      (__attribute__((address_space(3))) void*)l, 16, 0, 0);
}

#define BAR() asm volatile("s_barrier" ::: "memory")
#define LGKM0() asm volatile("s_waitcnt lgkmcnt(0)" ::: "memory")
#define VMW4() asm volatile("s_waitcnt vmcnt(4)" ::: "memory")
#define VMW0() asm volatile("s_waitcnt vmcnt(0)" ::: "memory")

// ---------------- fp32 -> bf16 bulk convert ----------------
__global__ __launch_bounds__(256) void cvt_f32_bf16(const float* __restrict__ in,
                                                    bfu* __restrict__ out, int n8) {
  const int stride = gridDim.x * blockDim.x;
  for (int i = blockIdx.x * blockDim.x + threadIdx.x; i < n8; i += stride) {
    const size_t off = (size_t)i * 8;
    fx4 a = *(const fx4*)(in + off);
    fx4 b = *(const fx4*)(in + off + 4);
    s16x8 o;
#pragma unroll
    for (int j = 0; j < 4; j++) {
      o[j] = (short)f2bf(a[j]);
      o[j + 4] = (short)f2bf(b[j]);
    }
    *reinterpret_cast<s16x8*>(out + off) = o;
  }
}

// ---------------- transpose + fp32->bf16 convert: out[c][r] = in[r][c] ----------------
template <int R, int CC>
__global__ __launch_bounds__(256) void transpose_cvt(const float* __restrict__ in,
                                                     bfu* __restrict__ out) {
  __shared__ float tile[32][33];
  const int bx = blockIdx.x, by = blockIdx.y, tx = threadIdx.x;
  for (int j = threadIdx.y; j < 32; j += 8)
    tile[j][tx] = in[(size_t)(by * 32 + j) * CC + bx * 32 + tx];
  __syncthreads();
  for (int j = threadIdx.y; j < 32; j += 8)
    out[(size_t)(bx * 32 + j) * R + by * 32 + tx] = f2bf(tile[tx][j]);
}

// =================== shared GEMM pieces ===================
// Rows in LDS are 64 B (32 bf16). Swizzle involution (both sides):
// slot' = slot ^ ((row>>1)&3)  <=>  byte ^= ((byte>>3)&48).  0 conflicts (R4 PMC).

__device__ __forceinline__ s16x8 lfrag(const bfu* region, int row, int lg) {
  const int lin = row * 64 + lg * 16;
  const int swz = lin ^ ((lin >> 3) & 48);
  return *reinterpret_cast<const s16x8*>(reinterpret_cast<const char*>(region) + swz);
}

// stage a [256 rows][32k] 16KB half (512-thread blocks)
template <int KD>
__device__ __forceinline__ void stage_half(const bfu* __restrict__ Mt, int r0, int kb,
                                           bfu* region, int t) {
#pragma unroll
  for (int h = 0; h < 2; h++) {
    const int u = t + h * 512;
    const int srow = u >> 2;
    const int sslot = (u & 3) ^ ((srow >> 1) & 3);
    gload_lds16(Mt + (size_t)(r0 + srow) * KD + kb + sslot * 8, region + u * 8);
  }
}

// stage [NR rows][32k] with 256-thread block
template <int KD, int NR>
__device__ __forceinline__ void stage_rows256(const bfu* __restrict__ Mt, int r0, int kb,
                                              bfu* region, int t) {
#pragma unroll
  for (int h = 0; h < NR / 64; h++) {
    const int u = t + h * 256;
    const int srow = u >> 2;
    const int sslot = (u & 3) ^ ((srow >> 1) & 3);
    gload_lds16(Mt + (size_t)(r0 + srow) * KD + kb + sslot * 8, region + u * 8);
  }
}

#define LF(bytoff) \
  (*reinterpret_cast<const s16x8*>(reinterpret_cast<const char*>(lds) + (bytoff)))

// ---------------- 256x256 8-phase GEMM (R4 structure, unchanged) ----------------
template <int MM, int N, int KD, bool OUT_BF16>
__global__ __launch_bounds__(512, 2) void gemm256(const bfu* __restrict__ A,
                                                  const bfu* __restrict__ Bt,
                                                  const float* __restrict__ bias,
                                                  void* __restrict__ Cptr) {
  __shared__ bfu lds[2 * 4 * 8192];  // 128 KiB
  const int t = threadIdx.x;
  const int lane = t & 63, wid = t >> 6;
  const int wr = wid >> 2, wc = wid & 3;
  const int lr = lane & 15, lg = lane >> 4;
  const int cpx = gridDim.x >> 3;
  const int li = (blockIdx.x & 7) * cpx + (blockIdx.x >> 3);
  const int row0 = (li % (MM / 256)) * 256;
  const int col0 = (li / (MM / 256)) * 256;
  constexpr int ntk = KD / 64;
  const int abase = ((wr * 128 + lr) * 64 + lg * 16) ^ (((lr >> 1) & 3) << 4);
  const int bbase = ((wc * 64 + lr) * 64 + lg * 16) ^ (((lr >> 1) & 3) << 4);

  fx4 acc[8][4] = {};

  stage_half<KD>(A, row0, 0, lds + 0, t);
  stage_half<KD>(Bt, col0, 0, lds + 16384, t);
  stage_half<KD>(A, row0, 32, lds + 8192, t);
  stage_half<KD>(Bt, col0, 32, lds + 24576, t);
  stage_half<KD>(A, row0, 64, lds + 32768 + 0, t);
  stage_half<KD>(Bt, col0, 64, lds + 32768 + 16384, t);
  VMW4();
  BAR();

  for (int tau = 0; tau < ntk; ++tau) {
    const int cbb = (tau & 1) ? 65536 : 0;
    bfu* nb_ = (tau & 1) ? lds : lds + 32768;
    s16x8 af[4], bf4[4];

#pragma unroll
    for (int m = 0; m < 4; m++) af[m] = LF(cbb + abase + m * 1024);
#pragma unroll
    for (int n = 0; n < 4; n++) bf4[n] = LF(cbb + 32768 + bbase + n * 1024);
    if (tau + 1 < ntk) stage_half<KD>(A, row0, (tau + 1) * 64 + 32, nb_ + 8192, t);
    BAR();
    LGKM0();
    __builtin_amdgcn_s_setprio(1);
#pragma unroll
    for (int m = 0; m < 4; m++)
#pragma unroll
      for (int n = 0; n < 4; n++)
        acc[m][n] = __builtin_amdgcn_mfma_f32_16x16x32_bf16(af[m], bf4[n], acc[m][n], 0, 0, 0);
    __builtin_amdgcn_s_setprio(0);
    BAR();

#pragma unroll
    for (int m = 0; m < 4; m++) af[m] = LF(cbb + abase + 4096 + m * 1024);
    if (tau + 1 < ntk) stage_half<KD>(Bt, col0, (tau + 1) * 64 + 32, nb_ + 24576, t);
    BAR();
    LGKM0();
    __builtin_amdgcn_s_setprio(1);
#pragma unroll
    for (int m = 0; m < 4; m++)
#pragma unroll
      for (int n = 0; n < 4; n++)
        acc[m + 4][n] = __builtin_amdgcn_mfma_f32_16x16x32_bf16(af[m], bf4[n], acc[m + 4][n], 0, 0, 0);
    __builtin_amdgcn_s_setprio(0);
    BAR();

#pragma unroll
    for (int m = 0; m < 4; m++) af[m] = LF(cbb + 16384 + abase + m * 1024);
#pragma unroll
    for (int n = 0; n < 4; n++) bf4[n] = LF(cbb + 49152 + bbase + n * 1024);
    if (tau + 2 < ntk) stage_half<KD>(A, row0, (tau + 2) * 64, lds + (cbb >> 1), t);
    BAR();
    LGKM0();
    __builtin_amdgcn_s_setprio(1);
#pragma unroll
    for (int m = 0; m < 4; m++)
#pragma unroll
      for (int n = 0; n < 4; n++)
        acc[m][n] = __builtin_amdgcn_mfma_f32_16x16x32_bf16(af[m], bf4[n], acc[m][n], 0, 0, 0);
    __builtin_amdgcn_s_setprio(0);
    BAR();

#pragma unroll
    for (int m = 0; m < 4; m++) af[m] = LF(cbb + 16384 + abase + 4096 + m * 1024);
    if (tau + 2 < ntk) stage_half<KD>(Bt, col0, (tau + 2) * 64, lds + (cbb >> 1) + 16384, t);
    BAR();
    LGKM0();
    __builtin_amdgcn_s_setprio(1);
#pragma unroll
    for (int m = 0; m < 4; m++)
#pragma unroll
      for (int n = 0; n < 4; n++)
        acc[m + 4][n] = __builtin_amdgcn_mfma_f32_16x16x32_bf16(af[m], bf4[n], acc[m + 4][n], 0, 0, 0);
    __builtin_amdgcn_s_setprio(0);
    if (tau < ntk - 1) {
      if (tau < ntk - 2) VMW4();
      else VMW0();
    }
    BAR();
  }

  float bv[4];
#pragma unroll
  for (int n = 0; n < 4; n++) bv[n] = bias[col0 + wc * 64 + n * 16 + lr];
#pragma unroll
  for (int m = 0; m < 8; m++)
#pragma unroll
    for (int n = 0; n < 4; n++)
#pragma unroll
      for (int r = 0; r < 4; r++) {
        const int row = row0 + wr * 128 + m * 16 + lg * 4 + r;
        const int col = col0 + wc * 64 + n * 16 + lr;
        const float v = acc[m][n][r] + bv[n];
        if constexpr (OUT_BF16)
          ((bfu*)Cptr)[(size_t)row * N + col] = f2bf(v);
        else
          ((float*)Cptr)[(size_t)row * N + col] = v;
      }
}

// ---------------- bulk GEMM: 256x128 tile, 4 waves (2x2), BK=32, 48KB LDS -------------
// One barrier pair per K-tile (32 MFMA); 2 blocks/CU provide cross-block overlap of
// the VMW0 drain and barrier (m97/m103 mechanism).  A [MM][KD], Bt [N][KD].
template <int MM, int N, int KD, bool OUT_BF16>
__global__ __launch_bounds__(256, 2) void gemm_bulk(const bfu* __restrict__ A,
                                                    const bfu* __restrict__ Bt,
                                                    const float* __restrict__ bias,
                                                    void* __restrict__ Cptr) {
  __shared__ bfu lds[24576];  // 48 KiB: buf = A[256][32] (8192 el) + B[128][32] (4096 el)
  const int t = threadIdx.x;
  const int lane = t & 63, wid = t >> 6;
  const int wr = wid >> 1, wc = wid & 1;  // 2x2 waves, wave-tile 128x64
  const int lr = lane & 15, lg = lane >> 4;
  const int cpx = gridDim.x >> 3;
  const int li = (blockIdx.x & 7) * cpx + (blockIdx.x >> 3);
  const int row0 = (li % (MM / 256)) * 256;
  const int col0 = (li / (MM / 256)) * 128;
  constexpr int ntk = KD / 32;
  const int abase = ((wr * 128 + lr) * 64 + lg * 16) ^ (((lr >> 1) & 3) << 4);
  const int bbase = 16384 + (((wc * 64 + lr) * 64 + lg * 16) ^ (((lr >> 1) & 3) << 4));

  fx4 acc[8][4] = {};

  stage_rows256<KD, 256>(A, row0, 0, lds + 0, t);
  stage_rows256<KD, 128>(Bt, col0, 0, lds + 8192, t);
  VMW0();
  BAR();

  for (int tau = 0; tau < ntk; ++tau) {
    const int cbb = (tau & 1) ? 24576 : 0;  // byte offset of current buffer
    bfu* nb_ = (tau & 1) ? lds : lds + 12288;
    if (tau + 1 < ntk) {
      stage_rows256<KD, 256>(A, row0, (tau + 1) * 32, nb_ + 0, t);
      stage_rows256<KD, 128>(Bt, col0, (tau + 1) * 32, nb_ + 8192, t);
    }
    s16x8 af[8], bf4[4];
#pragma unroll
    for (int m = 0; m < 8; m++) af[m] = LF(cbb + abase + m * 1024);
#pragma unroll
    for (int n = 0; n < 4; n++) bf4[n] = LF(cbb + bbase + n * 1024);
    __builtin_amdgcn_s_setprio(1);
#pragma unroll
    for (int m = 0; m < 8; m++)
#pragma unroll
      for (int n = 0; n < 4; n++)
        acc[m][n] = __builtin_amdgcn_mfma_f32_16x16x32_bf16(af[m], bf4[n], acc[m][n], 0, 0, 0);
    __builtin_amdgcn_s_setprio(0);
    LGKM0();  // all this tile's ds_reads serviced before the barrier (stage hazard)
    VMW0();   // next tile's stage complete
    BAR();
  }

  float bv[4];
#pragma unroll
  for (int n = 0; n < 4; n++) bv[n] = bias[col0 + wc * 64 + n * 16 + lr];
#pragma unroll
  for (int m = 0; m < 8; m++)
#pragma unroll
    for (int n = 0; n < 4; n++)
#pragma unroll
      for (int r = 0; r < 4; r++) {
        const int row = row0 + wr * 128 + m * 16 + lg * 4 + r;
        const int col = col0 + wc * 64 + n * 16 + lr;
        const float v = acc[m][n][r] + bv[n];
        if constexpr (OUT_BF16)
          ((bfu*)Cptr)[(size_t)row * N + col] = f2bf(v);
        else
          ((float*)Cptr)[(size_t)row * N + col] = v;
      }
}

// ---------------- depthwise causal conv K=4, sliding window ----------------
__global__ __launch_bounds__(256) void dwconv_slide(const bfu* __restrict__ xe,
                                                    const float* __restrict__ cw,
                                                    const float* __restrict__ cb,
                                                    bfu* __restrict__ y) {
  const int nchunk = L_ / LCH;
  const int b = blockIdx.x / nchunk;
  const int l0 = (blockIdx.x % nchunk) * LCH;
  const int cg = threadIdx.x << 3;

  float w[4][8], bias8[8];
#pragma unroll
  for (int tt = 0; tt < 4; tt++) {
    fx4 w0 = *(const fx4*)(cw + tt * C_ + cg);
    fx4 w1 = *(const fx4*)(cw + tt * C_ + cg + 4);
#pragma unroll
    for (int i = 0; i < 4; i++) {
      w[tt][i] = w0[i];
      w[tt][i + 4] = w1[i];
    }
  }
  {
    fx4 c0 = *(const fx4*)(cb + cg), c1 = *(const fx4*)(cb + cg + 4);
#pragma unroll
    for (int i = 0; i < 4; i++) {
      bias8[i] = c0[i];
      bias8[i + 4] = c1[i];
    }
  }

  const size_t base = ((size_t)b * L_ + l0) * C_ + cg;
  s16x8 h0 = {}, h1 = {}, h2 = {};
  if (l0 != 0) {
    h0 = *reinterpret_cast<const s16x8*>(xe + base - 3 * C_);
    h1 = *reinterpret_cast<const s16x8*>(xe + base - 2 * C_);
    h2 = *reinterpret_cast<const s16x8*>(xe + base - 1 * C_);
  }
#pragma unroll
  for (int i = 0; i < LCH; i++) {
    s16x8 h3 = *reinterpret_cast<const s16x8*>(xe + base + (size_t)i * C_);
    s16x8 o;
#pragma unroll
    for (int j = 0; j < 8; j++) {
      float v = bias8[j];
      v = fmaf(bits2f(h0[j]), w[0][j], v);
      v = fmaf(bits2f(h1[j]), w[1][j], v);
      v = fmaf(bits2f(h2[j]), w[2][j], v);
      v = fmaf(bits2f(h3[j]), w[3][j], v);
      o[j] = (short)f2bf(v);
    }
    *reinterpret_cast<s16x8*>(y + base + (size_t)i * C_) = o;
    h0 = h1;
    h1 = h2;
    h2 = h3;
  }
}

extern "C" void kernel_launch(void* const* d_in, const int* in_sizes, int n_in,
                              void* d_out, int out_size, void* d_ws, size_t ws_size,
                              hipStream_t stream) {
  const float* x = (const float*)d_in[0];
  const float* W_exp = (const float*)d_in[1];
  const float* b_exp = (const float*)d_in[2];
  const float* cw = (const float*)d_in[3];
  const float* cb = (const float*)d_in[4];
  const float* W_cmp = (const float*)d_in[5];
  const float* b_cmp = (const float*)d_in[6];
  float* out = (float*)d_out;

  char* ws = (char*)d_ws;
  bfu* wexp_t = (bfu*)(ws);                // [C][D] bf16, 4 MiB
  bfu* wcmp_t = (bfu*)(ws + (4u << 20));   // [D][C] bf16, 4 MiB
  bfu* xb = (bfu*)(ws + (8u << 20));       // [M][D] bf16, 32 MiB
  bfu* xe = (bfu*)(ws + (40u << 20));      // [M][C] bf16, 64 MiB
  bfu* y = (bfu*)(ws + (104u << 20));      // [M][C] bf16, 64 MiB

  cvt_f32_bf16<<<2048, 256, 0, stream>>>(x, xb, M_ * D_ / 8);
  transpose_cvt<D_, C_><<<dim3(C_ / 32, D_ / 32), dim3(32, 8), 0, stream>>>(W_exp, wexp_t);
  transpose_cvt<C_, D_><<<dim3(D_ / 32, C_ / 32), dim3(32, 8), 0, stream>>>(W_cmp, wcmp_t);
  // expand GEMM (8-phase structure, unchanged): xe = x @ W_exp + b_exp
  gemm256<M_, C_, D_, true><<<512, 512, 0, stream>>>(xb, wexp_t, b_exp, xe);
  // conv
  dwconv_slide<<<B_ * (L_ / LCH), 256, 0, stream>>>(xe, cw, cb, y);
  // compress GEMM (NEW bulk structure, A/B test): out = y @ W_cmp + b_cmp
  // grid = (16384/256) * (1024/128) = 64*8 = 512 blocks, 2 per CU resident
  gemm_bulk<M_, D_, C_, false><<<512, 256, 0, stream>>>(y, wcmp_t, b_cmp, out);
}

// Round 7
// 200.979 us; speedup vs baseline: 1.0905x; 1.0905x over previous
//
#include <hip/hip_runtime.h>
#include <stdint.h>

#define B_ 4
#define L_ 4096
#define D_ 1024
#define C_ 2048
#define M_ (B_ * L_)  // 16384
#define LCH 16        // conv l-chunk per block

typedef __attribute__((ext_vector_type(8))) short s16x8;
typedef __attribute__((ext_vector_type(4))) float fx4;
typedef unsigned short bfu;  // bf16 bits

__device__ __forceinline__ float bits2f(short s) {
  return __uint_as_float(((uint32_t)(unsigned short)s) << 16);
}
__device__ __forceinline__ bfu f2bf(float f) {
  uint32_t u = __float_as_uint(f);
  uint32_t r = (u + 0x7FFFu + ((u >> 16) & 1u)) >> 16;  // RNE
  return (bfu)r;
}

__device__ __forceinline__ void gload_lds16(const void* g, void* l) {
  __builtin_amdgcn_global_load_lds(
      (const __attribute__((address_space(1))) void*)g,
      (__attribute__((address_space(3))) void*)l, 16, 0, 0);
}

#define BAR() asm volatile("s_barrier" ::: "memory")
#define LGKM0() asm volatile("s_waitcnt lgkmcnt(0)" ::: "memory")
#define VMW8() asm volatile("s_waitcnt vmcnt(8)" ::: "memory")
#define VMW4() asm volatile("s_waitcnt vmcnt(4)" ::: "memory")
#define VMW0() asm volatile("s_waitcnt vmcnt(0)" ::: "memory")

// ---------------- fp32 -> bf16 bulk convert ----------------
__global__ __launch_bounds__(256) void cvt_f32_bf16(const float* __restrict__ in,
                                                    bfu* __restrict__ out, int n8) {
  const int stride = gridDim.x * blockDim.x;
  for (int i = blockIdx.x * blockDim.x + threadIdx.x; i < n8; i += stride) {
    const size_t off = (size_t)i * 8;
    fx4 a = *(const fx4*)(in + off);
    fx4 b = *(const fx4*)(in + off + 4);
    s16x8 o;
#pragma unroll
    for (int j = 0; j < 4; j++) {
      o[j] = (short)f2bf(a[j]);
      o[j + 4] = (short)f2bf(b[j]);
    }
    *reinterpret_cast<s16x8*>(out + off) = o;
  }
}

// ---------------- transpose + fp32->bf16 convert: out[c][r] = in[r][c] ----------------
template <int R, int CC>
__global__ __launch_bounds__(256) void transpose_cvt(const float* __restrict__ in,
                                                     bfu* __restrict__ out) {
  __shared__ float tile[32][33];
  const int bx = blockIdx.x, by = blockIdx.y, tx = threadIdx.x;
  for (int j = threadIdx.y; j < 32; j += 8)
    tile[j][tx] = in[(size_t)(by * 32 + j) * CC + bx * 32 + tx];
  __syncthreads();
  for (int j = threadIdx.y; j < 32; j += 8)
    out[(size_t)(bx * 32 + j) * R + by * 32 + tx] = f2bf(tile[tx][j]);
}

// =================== 256x256 8-phase GEMM ===================
// LDS buffer (elements): A-kh0 @0, A-kh1 @8192, B-kh0 @16384, B-kh1 @24576;
// buf1 = +32768.  Rows are 64 B (32 bf16).  Swizzle involution (both sides):
// slot' = slot ^ ((row>>1)&3)  <=>  byte ^= ((byte>>3)&48).  0 conflicts (R4 PMC).
// vmcnt schedule (R7): 8 loads = 4 half-tiles permanently in flight; waits
// VMW8 at end-P2 (drains cur kh1) and end-P4 (drains next kh0), so every
// waited load is >= 4 phases (~1700 cy) old vs ~900 cy HBM latency.

template <int KD>
__device__ __forceinline__ void stage_half(const bfu* __restrict__ Mt, int r0, int kb,
                                           bfu* region, int t) {
#pragma unroll
  for (int h = 0; h < 2; h++) {
    const int u = t + h * 512;
    const int srow = u >> 2;
    const int sslot = (u & 3) ^ ((srow >> 1) & 3);
    gload_lds16(Mt + (size_t)(r0 + srow) * KD + kb + sslot * 8, region + u * 8);
  }
}

#define LF(bytoff) \
  (*reinterpret_cast<const s16x8*>(reinterpret_cast<const char*>(lds) + (bytoff)))

template <int MM, int N, int KD, bool OUT_BF16>
__global__ __launch_bounds__(512, 2) void gemm256(const bfu* __restrict__ A,
                                                  const bfu* __restrict__ Bt,
                                                  const float* __restrict__ bias,
                                                  void* __restrict__ Cptr) {
  __shared__ bfu lds[2 * 4 * 8192];  // 128 KiB
  const int t = threadIdx.x;
  const int lane = t & 63, wid = t >> 6;
  const int wr = wid >> 2, wc = wid & 3;
  const int lr = lane & 15, lg = lane >> 4;
  const int cpx = gridDim.x >> 3;
  const int li = (blockIdx.x & 7) * cpx + (blockIdx.x >> 3);
  const int row0 = (li % (MM / 256)) * 256;
  const int col0 = (li / (MM / 256)) * 256;
  constexpr int ntk = KD / 64;
  const int abase = ((wr * 128 + lr) * 64 + lg * 16) ^ (((lr >> 1) & 3) << 4);
  const int bbase = ((wc * 64 + lr) * 64 + lg * 16) ^ (((lr >> 1) & 3) << 4);

  fx4 acc[8][4] = {};

  // prologue: tile0 all 4 halves + tile1 kh0 halves = 12 loads; drain only
  // tile0's A0,B0 (oldest 4) -> VMW8.
  stage_half<KD>(A, row0, 0, lds + 0, t);
  stage_half<KD>(Bt, col0, 0, lds + 16384, t);
  stage_half<KD>(A, row0, 32, lds + 8192, t);
  stage_half<KD>(Bt, col0, 32, lds + 24576, t);
  stage_half<KD>(A, row0, 64, lds + 32768 + 0, t);
  stage_half<KD>(Bt, col0, 64, lds + 32768 + 16384, t);
  VMW8();
  BAR();

  for (int tau = 0; tau < ntk; ++tau) {
    const int cbb = (tau & 1) ? 65536 : 0;
    bfu* nb_ = (tau & 1) ? lds : lds + 32768;
    s16x8 af[4], bf4[4];

    // ---- P1: kh0, m0-3 x n0-3 | stage (tau+1).A-kh1 -> nb_
#pragma unroll
    for (int m = 0; m < 4; m++) af[m] = LF(cbb + abase + m * 1024);
#pragma unroll
    for (int n = 0; n < 4; n++) bf4[n] = LF(cbb + 32768 + bbase + n * 1024);
    if (tau + 1 < ntk) stage_half<KD>(A, row0, (tau + 1) * 64 + 32, nb_ + 8192, t);
    BAR();
    LGKM0();
    __builtin_amdgcn_s_setprio(1);
#pragma unroll
    for (int m = 0; m < 4; m++)
#pragma unroll
      for (int n = 0; n < 4; n++)
        acc[m][n] = __builtin_amdgcn_mfma_f32_16x16x32_bf16(af[m], bf4[n], acc[m][n], 0, 0, 0);
    __builtin_amdgcn_s_setprio(0);
    BAR();

    // ---- P2: kh0, m4-7 (reuse bf4) | stage (tau+1).B-kh1 -> nb_ | W1
#pragma unroll
    for (int m = 0; m < 4; m++) af[m] = LF(cbb + abase + 4096 + m * 1024);
    if (tau + 1 < ntk) stage_half<KD>(Bt, col0, (tau + 1) * 64 + 32, nb_ + 24576, t);
    BAR();
    LGKM0();
    __builtin_amdgcn_s_setprio(1);
#pragma unroll
    for (int m = 0; m < 4; m++)
#pragma unroll
      for (int n = 0; n < 4; n++)
        acc[m + 4][n] = __builtin_amdgcn_mfma_f32_16x16x32_bf16(af[m], bf4[n], acc[m + 4][n], 0, 0, 0);
    __builtin_amdgcn_s_setprio(0);
    // need (tau).A-kh1,B-kh1 before P3 reads; 8 newer loads may stay in flight
    if (tau < ntk - 1) VMW8();
    else VMW0();
    BAR();

    // ---- P3: kh1, m0-3 x n0-3 | stage (tau+2).A-kh0 -> cb_ (kh0 dead after P2)
#pragma unroll
    for (int m = 0; m < 4; m++) af[m] = LF(cbb + 16384 + abase + m * 1024);
#pragma unroll
    for (int n = 0; n < 4; n++) bf4[n] = LF(cbb + 49152 + bbase + n * 1024);
    if (tau + 2 < ntk) stage_half<KD>(A, row0, (tau + 2) * 64, lds + (cbb >> 1), t);
    BAR();
    LGKM0();
    __builtin_amdgcn_s_setprio(1);
#pragma unroll
    for (int m = 0; m < 4; m++)
#pragma unroll
      for (int n = 0; n < 4; n++)
        acc[m][n] = __builtin_amdgcn_mfma_f32_16x16x32_bf16(af[m], bf4[n], acc[m][n], 0, 0, 0);
    __builtin_amdgcn_s_setprio(0);
    BAR();

    // ---- P4: kh1, m4-7 (reuse bf4) | stage (tau+2).B-kh0 -> cb_ | W2
#pragma unroll
    for (int m = 0; m < 4; m++) af[m] = LF(cbb + 16384 + abase + 4096 + m * 1024);
    if (tau + 2 < ntk) stage_half<KD>(Bt, col0, (tau + 2) * 64, lds + (cbb >> 1) + 16384, t);
    BAR();
    LGKM0();
    __builtin_amdgcn_s_setprio(1);
#pragma unroll
    for (int m = 0; m < 4; m++)
#pragma unroll
      for (int n = 0; n < 4; n++)
        acc[m + 4][n] = __builtin_amdgcn_mfma_f32_16x16x32_bf16(af[m], bf4[n], acc[m + 4][n], 0, 0, 0);
    __builtin_amdgcn_s_setprio(0);
    // need (tau+1).A-kh0,B-kh0 before next P1
    if (tau < ntk - 2) VMW8();
    else if (tau == ntk - 2) VMW4();
    BAR();
  }

  // epilogue: C/D layout col=lane&15, row=(lane>>4)*4+reg
  float bv[4];
#pragma unroll
  for (int n = 0; n < 4; n++) bv[n] = bias[col0 + wc * 64 + n * 16 + lr];
#pragma unroll
  for (int m = 0; m < 8; m++)
#pragma unroll
    for (int n = 0; n < 4; n++)
#pragma unroll
      for (int r = 0; r < 4; r++) {
        const int row = row0 + wr * 128 + m * 16 + lg * 4 + r;
        const int col = col0 + wc * 64 + n * 16 + lr;
        const float v = acc[m][n][r] + bv[n];
        if constexpr (OUT_BF16)
          ((bfu*)Cptr)[(size_t)row * N + col] = f2bf(v);
        else
          ((float*)Cptr)[(size_t)row * N + col] = v;
      }
}

// ---------------- depthwise causal conv K=4, sliding window ----------------
__global__ __launch_bounds__(256) void dwconv_slide(const bfu* __restrict__ xe,
                                                    const float* __restrict__ cw,
                                                    const float* __restrict__ cb,
                                                    bfu* __restrict__ y) {
  const int nchunk = L_ / LCH;
  const int b = blockIdx.x / nchunk;
  const int l0 = (blockIdx.x % nchunk) * LCH;
  const int cg = threadIdx.x << 3;

  float w[4][8], bias8[8];
#pragma unroll
  for (int tt = 0; tt < 4; tt++) {
    fx4 w0 = *(const fx4*)(cw + tt * C_ + cg);
    fx4 w1 = *(const fx4*)(cw + tt * C_ + cg + 4);
#pragma unroll
    for (int i = 0; i < 4; i++) {
      w[tt][i] = w0[i];
      w[tt][i + 4] = w1[i];
    }
  }
  {
    fx4 c0 = *(const fx4*)(cb + cg), c1 = *(const fx4*)(cb + cg + 4);
#pragma unroll
    for (int i = 0; i < 4; i++) {
      bias8[i] = c0[i];
      bias8[i + 4] = c1[i];
    }
  }

  const size_t base = ((size_t)b * L_ + l0) * C_ + cg;
  s16x8 h0 = {}, h1 = {}, h2 = {};
  if (l0 != 0) {
    h0 = *reinterpret_cast<const s16x8*>(xe + base - 3 * C_);
    h1 = *reinterpret_cast<const s16x8*>(xe + base - 2 * C_);
    h2 = *reinterpret_cast<const s16x8*>(xe + base - 1 * C_);
  }
#pragma unroll
  for (int i = 0; i < LCH; i++) {
    s16x8 h3 = *reinterpret_cast<const s16x8*>(xe + base + (size_t)i * C_);
    s16x8 o;
#pragma unroll
    for (int j = 0; j < 8; j++) {
      float v = bias8[j];
      v = fmaf(bits2f(h0[j]), w[0][j], v);
      v = fmaf(bits2f(h1[j]), w[1][j], v);
      v = fmaf(bits2f(h2[j]), w[2][j], v);
      v = fmaf(bits2f(h3[j]), w[3][j], v);
      o[j] = (short)f2bf(v);
    }
    *reinterpret_cast<s16x8*>(y + base + (size_t)i * C_) = o;
    h0 = h1;
    h1 = h2;
    h2 = h3;
  }
}

extern "C" void kernel_launch(void* const* d_in, const int* in_sizes, int n_in,
                              void* d_out, int out_size, void* d_ws, size_t ws_size,
                              hipStream_t stream) {
  const float* x = (const float*)d_in[0];
  const float* W_exp = (const float*)d_in[1];
  const float* b_exp = (const float*)d_in[2];
  const float* cw = (const float*)d_in[3];
  const float* cb = (const float*)d_in[4];
  const float* W_cmp = (const float*)d_in[5];
  const float* b_cmp = (const float*)d_in[6];
  float* out = (float*)d_out;

  char* ws = (char*)d_ws;
  bfu* wexp_t = (bfu*)(ws);                // [C][D] bf16, 4 MiB
  bfu* wcmp_t = (bfu*)(ws + (4u << 20));   // [D][C] bf16, 4 MiB
  bfu* xb = (bfu*)(ws + (8u << 20));       // [M][D] bf16, 32 MiB
  bfu* xe = (bfu*)(ws + (40u << 20));      // [M][C] bf16, 64 MiB
  bfu* y = (bfu*)(ws + (104u << 20));      // [M][C] bf16, 64 MiB

  cvt_f32_bf16<<<2048, 256, 0, stream>>>(x, xb, M_ * D_ / 8);
  transpose_cvt<D_, C_><<<dim3(C_ / 32, D_ / 32), dim3(32, 8), 0, stream>>>(W_exp, wexp_t);
  transpose_cvt<C_, D_><<<dim3(D_ / 32, C_ / 32), dim3(32, 8), 0, stream>>>(W_cmp, wcmp_t);
  // expand GEMM: xe = x @ W_exp + b_exp
  gemm256<M_, C_, D_, true><<<512, 512, 0, stream>>>(xb, wexp_t, b_exp, xe);
  // conv
  dwconv_slide<<<B_ * (L_ / LCH), 256, 0, stream>>>(xe, cw, cb, y);
  // compress GEMM: out = y @ W_cmp + b_cmp
  gemm256<M_, D_, C_, false><<<256, 512, 0, stream>>>(y, wcmp_t, b_cmp, out);
}